// Round 11
// baseline (90.363 us; speedup 1.0000x reference)
//
#include <hip/hip_runtime.h>

// SpikingLayer forward: first-spike times of a delayed-synapse LIF layer.
// B=128, I=512+1 bias, O=512, STEPS=200.
// R10: persistent-worker queue. R9 baseline (79.2us bench = ~35us snn +
// ~44us harness fill floor) runs grid=1024 at 3 resident blocks/CU ->
// TWO dispatch rounds, the 2nd ragged (256 blocks, 1/CU, no cross-block
// latency hiding) => ~2x tile-time instead of 4/3x. Fix: grid=768 (exactly
// 3/CU), each block pops (b,otile) tiles off a global atomic counter until
// 1024 consumed -> each CU's 3 workers process ~4 tiles, balanced, no
// inter-round bubble. Tile body is byte-identical to R9 (the R6-R8 scratch
// leak came from intra-body control flow; queue adds only a loop-top pop).
// Queue counter in d_ws after wI, zeroed by prep each call (graph-safe).
// Numerics unchanged: bin = (float)((double)arr*10000.0) (exact f64 product,
// RNE cvt == IEEE f32 divide bit-for-bit), deterministic fixed-point
// ds_add_u32 binning, contract off, exact sequential phase 2 + early exit.

#define IN_F    512
#define OUT_F   512
#define BATCH   128
#define STEPS   200
#define NTILES  1024                         // 128 batches x 8 otiles
#define NWORK   768                          // 3 blocks/CU x 256 CUs
#define RES_F   1e-4f
#define CSTRIDE 65                           // stride-65: bank=(s+col)%32
// double exp(-1e-4/5e-3) = exp(-0.02), rounded to f32 by the literal:
#define DECAY_F 0.98019867330675525f
// double (1.0 - exp(-0.02)), rounded to f32:
#define ONEMD_F 0.019801326693244747f
#define SIM_T_F 2e-2f
#define FPSCALE 8388608.0f                   // 2^23
#define INVSCALE 1.1920928955078125e-07f     // 2^-23, exact
#define QOFF    ((IN_F + 1) * OUT_F)         // queue counter: wI[QOFF]

// q = fl32(arr / 1e-4f) computed exactly: (double)arr*10000.0 is exact,
// double->float is RNE == the IEEE f32 division result, bit for bit.
__device__ __forceinline__ int bin_of(float arr) {
    float q = (float)((double)arr * 10000.0);
    int s = __float2int_rn(q);               // RNE == np.round half-to-even
    s = s < 0 ? 0 : (s > STEPS - 1 ? STEPS - 1 : s);
    return s;
}

__global__ __launch_bounds__(256) void prep_wi(
    const float* __restrict__ weights, int* __restrict__ wI)
{
    int idx = blockIdx.x * 256 + threadIdx.x;        // float4 index
    if (idx < (IN_F + 1) * OUT_F / 4) {
        float4 v = ((const float4*)weights)[idx];
        int4 r;
        r.x = __float2int_rn(v.x * FPSCALE);
        r.y = __float2int_rn(v.y * FPSCALE);
        r.z = __float2int_rn(v.z * FPSCALE);
        r.w = __float2int_rn(v.w * FPSCALE);
        ((int4*)wI)[idx] = r;
    }
    if (blockIdx.x == 0 && threadIdx.x == 0)
        wI[QOFF] = 0;                        // reset the work-queue counter
}

__global__ __launch_bounds__(512, 6) void snn_fwd(
    const float* __restrict__ input_times,   // [B, IN_F]
    int*         __restrict__ wI,            // [IN_F+1, OUT_F] fx-pt + queue
    const float* __restrict__ delays,        // [IN_F+1, OUT_F]
    const float* __restrict__ thresholds,    // [OUT_F]
    float* __restrict__ out)                 // [B, OUT_F]
{
#pragma clang fp contract(off)
    __shared__ __align__(16) int chargeI[STEPS * CSTRIDE];   // 52000 B
    __shared__ float times_s[IN_F];
    __shared__ int tile_s;

    const int tid  = threadIdx.x;
    const int wv   = tid >> 6;               // wave 0..7
    const int lane = tid & 63;
    const int sub = lane >> 4;               // 0..3
    const int cg  = (lane & 15) << 2;        // 0,4,...,60
    const int4*   __restrict__ Wp = (const int4*)wI;
    const float4* __restrict__ Dp = (const float4*)delays;
    const int r0   = wv << 6;                                // first row
    const int gstr = 4 * (OUT_F / 4);                        // 4 rows of vec4s

    for (;;) {
        if (tid == 0) tile_s = atomicAdd(&wI[QOFF], 1);      // pop a tile
        __syncthreads();     // publishes tile_s; also fences prev phase 2
        const int tile = tile_s;
        if (tile >= NTILES) break;                           // uniform exit
        const int b  = tile >> 3;
        const int ob = (tile & 7) << 6;      // output-column base

        // zero charge bins (int4) + stage this batch's input times
        {
            int4 z = make_int4(0, 0, 0, 0);
            int4* c4 = (int4*)chargeI;
            #pragma unroll
            for (int k = tid; k < (STEPS * CSTRIDE) / 4; k += 512) c4[k] = z;
        }
        times_s[tid] = input_times[b * IN_F + tid];   // IN_F == blockDim
        __syncthreads();

        // --- Phase 1: bin synapse charges ---
        // lane -> (row-offset sub, column-group cg): one 16B load covers
        // 4 rows x 64 cols per wave. Wave wv handles rows [64*wv, 64*wv+64).
        const int i0 = (r0 + sub) * (OUT_F / 4) + ((ob + cg) >> 2);

        // bias row (i=512, spike time 0): wave 7, one column per lane
        if (wv == 7) {
            float dl = delays[IN_F * OUT_F + ob + lane];
            int   wt = wI[IN_F * OUT_F + ob + lane];
            atomicAdd(&chargeI[bin_of(dl) * CSTRIDE + lane], wt);
        }

        // static depth-2 ping-pong over 16 vec4-steps (fully unrolled)
        int4   wA = Wp[i0],            wB = Wp[i0 + gstr];
        float4 dA = Dp[i0],            dB = Dp[i0 + gstr];
        float  tA = times_s[r0 + sub];
        float  tB = times_s[r0 + 4 + sub];

        #pragma unroll
        for (int g = 0; g < 16; g += 2) {
            int4   wC = {}, wD = {};
            float4 dC = {}, dD = {};
            float  tC = 0.f, tD = 0.f;
            if (g + 2 < 16) {
                wC = Wp[i0 + (g + 2) * gstr]; dC = Dp[i0 + (g + 2) * gstr];
                tC = times_s[r0 + ((g + 2) << 2) + sub];
            }
            if (g + 3 < 16) {
                wD = Wp[i0 + (g + 3) * gstr]; dD = Dp[i0 + (g + 3) * gstr];
                tD = times_s[r0 + ((g + 3) << 2) + sub];
            }
            {   // consume step g
                const float* dv = (const float*)&dA;
                const int*   wi = (const int*)&wA;
                #pragma unroll
                for (int k = 0; k < 4; ++k) {
                    int s = bin_of(tA + dv[k]);
                    atomicAdd(&chargeI[s * CSTRIDE + cg + k], wi[k]);
                }
            }
            {   // consume step g+1
                const float* dv = (const float*)&dB;
                const int*   wi = (const int*)&wB;
                #pragma unroll
                for (int k = 0; k < 4; ++k) {
                    int s = bin_of(tB + dv[k]);
                    atomicAdd(&chargeI[s * CSTRIDE + cg + k], wi[k]);
                }
            }
            wA = wC; dA = dC; tA = tC;
            wB = wD; dB = dD; tB = tD;
        }
        __syncthreads();

        // --- Phase 2 (wave 0 only): exact sequential leaky integration ---
        if (wv == 0) {
            const float thr = thresholds[ob + lane];
            float syn = 0.f, mem = 0.f, spike_t = SIM_T_F;
            bool spiked = false;
            for (int t0 = 0; t0 < STEPS; t0 += 4) {
                float c[4];
                #pragma unroll
                for (int j = 0; j < 4; ++j)           // batch the ds_reads
                    c[j] = (float)chargeI[(t0 + j) * CSTRIDE + lane] * INVSCALE;
                #pragma unroll
                for (int j = 0; j < 4; ++j) {
                    float syn_n = syn * DECAY_F + c[j];               // no fma
                    float mem_n = mem * DECAY_F + ONEMD_F * syn_n;    // no fma
                    if (!spiked && mem_n >= thr) {
                        float denom = mem_n - mem;
                        float safe  = fabsf(denom) > 1e-12f ? denom : 1e-12f;
                        float frac  = (thr - mem) / safe;
                        frac = frac < 0.f ? 0.f : (frac > 1.f ? 1.f : frac);
                        spike_t = ((float)(t0 + j) + frac) * RES_F;
                        spiked  = true;
                    }
                    syn = syn_n; mem = mem_n;
                }
                if (__all(spiked)) break;    // all 64 lanes latched
            }
            out[b * OUT_F + ob + lane] = spike_t;
        }
        // next loop iteration's pop-sync fences chargeI reuse
    }
}

extern "C" void kernel_launch(void* const* d_in, const int* in_sizes, int n_in,
                              void* d_out, int out_size, void* d_ws, size_t ws_size,
                              hipStream_t stream) {
    const float* input_times = (const float*)d_in[0];   // [128, 512]
    const float* weights     = (const float*)d_in[1];   // [513, 512]
    const float* delays      = (const float*)d_in[2];   // [513, 512]
    const float* thresholds  = (const float*)d_in[3];   // [512]
    float* out = (float*)d_out;                         // [128, 512]
    int*   wI  = (int*)d_ws;                 // [513*512] fixed-pt + counter

    // prologue: weights -> fixed-point + queue counter reset (every call)
    int nvec4 = (IN_F + 1) * OUT_F / 4;                 // 65664
    prep_wi<<<(nvec4 + 255) / 256, 256, 0, stream>>>(weights, wI);

    dim3 grid(NWORK);                  // 768 persistent workers, 3/CU
    snn_fwd<<<grid, 512, 0, stream>>>(input_times, wI, delays, thresholds, out);
}